// Round 4
// baseline (390.873 us; speedup 1.0000x reference)
//
#include <hip/hip_runtime.h>
#include <stdint.h>
#include <math.h>

#define BB 8
#define LL 2048
#define DT 32
#define HID 544
#define REGP 5.0f
#define BETA0 0.4f
#define BETA1 0.3f
#define EPSV 1e-6f

typedef float v4 __attribute__((ext_vector_type(4)));

__device__ __forceinline__ void fast_sincos(float x, float* s, float* c) {
    // x in radians, |x| < ~2100. Convert to revolutions, take fract, use HW.
    const float inv2pi = 0.15915494309189535f;
    float r = x * inv2pi;
    float f = r - floorf(r);
    *s = __builtin_amdgcn_sinf(f);
    *c = __builtin_amdgcn_cosf(f);
}

// Kernel A: 8 rows per block. hidden_vector (544 f32) + pre-exponentiated
// per-row scalars: paE=exp(pa_j), pbE=exp(pb_i+bl), gaE=exp(-5*ga_j),
// gbE=exp(-5*(gb_i+bg)).
__global__ __launch_bounds__(256) void prep_k(
    const int* __restrict__ etype, const float* __restrict__ etime,
    const float* __restrict__ wtpos, const float* __restrict__ temb,
    const float* __restrict__ wl, const float* __restrict__ wg,
    const float* __restrict__ blp, const float* __restrict__ bgp,
    float* __restrict__ hidden,
    float* __restrict__ paE, float* __restrict__ pbE,
    float* __restrict__ gaE, float* __restrict__ gbE)
{
    const int r0 = blockIdx.x << 3;      // first row (b*L+i) of this block
    const int tid = threadIdx.x;
    const float cdiv = -0.03597789207803197f;   // -ln(10000)/256
    const float divt = __expf((float)tid * cdiv);
    const float wt = wtpos[tid];
    const float bl = blp[0];
    const float bg = bgp[0];

    #pragma unroll
    for (int rr = 0; rr < 8; ++rr) {
        const int row = r0 + rr;
        const int i = row & (LL - 1);
        const float t = etime[row];
        float arc = fmaf((float)i, divt, t * wt);
        float sv, cv;
        fast_sincos(arc, &sv, &cv);
        size_t hbase = (size_t)row * HID;
        __builtin_nontemporal_store(sv, hidden + hbase + tid);
        __builtin_nontemporal_store(cv, hidden + hbase + 256 + tid);

        if (tid < 32) {
            int ty = etype[row];
            float te = temb[ty * DT + tid];
            __builtin_nontemporal_store(te, hidden + hbase + 512 + tid);
            float va = te * wl[tid];
            float vb = te * wl[32 + tid];
            float vc = te * wg[tid];
            float vd = te * wg[32 + tid];
            #pragma unroll
            for (int m = 16; m > 0; m >>= 1) {
                va += __shfl_xor(va, m, 64);
                vb += __shfl_xor(vb, m, 64);
                vc += __shfl_xor(vc, m, 64);
                vd += __shfl_xor(vd, m, 64);
            }
            if (tid == 0) {
                paE[row] = __expf(va);
                pbE[row] = __expf(vb + bl);
                gaE[row] = __expf(-REGP * vc);
                gbE[row] = __expf(-REGP * (vd + bg));
            }
        }
    }
}

// Kernel B: scores + t_diff (f32, non-temporal). One block covers a full
// 2048-wide j row set for a 16-row i-tile; 256 threads x 8 j each.
__global__ __launch_bounds__(256) void pair_k(
    const float* __restrict__ etime,
    const float* __restrict__ paE, const float* __restrict__ pbE,
    const float* __restrict__ gaE, const float* __restrict__ gbE,
    float* __restrict__ scores, float* __restrict__ tdiff)
{
    const int b  = blockIdx.y;
    const int i0 = blockIdx.x << 4;
    const int j0 = threadIdx.x << 3;
    const int rowb = b * LL;

    float tj[8], pj[8], gj[8];
    {
        const v4 t0 = *(const v4*)(etime + rowb + j0);
        const v4 t1 = *(const v4*)(etime + rowb + j0 + 4);
        tj[0]=t0.x; tj[1]=t0.y; tj[2]=t0.z; tj[3]=t0.w;
        tj[4]=t1.x; tj[5]=t1.y; tj[6]=t1.z; tj[7]=t1.w;
        const v4 p0 = *(const v4*)(paE + rowb + j0);
        const v4 p1 = *(const v4*)(paE + rowb + j0 + 4);
        pj[0]=p0.x; pj[1]=p0.y; pj[2]=p0.z; pj[3]=p0.w;
        pj[4]=p1.x; pj[5]=p1.y; pj[6]=p1.z; pj[7]=p1.w;
        const v4 g0 = *(const v4*)(gaE + rowb + j0);
        const v4 g1 = *(const v4*)(gaE + rowb + j0 + 4);
        gj[0]=g0.x; gj[1]=g0.y; gj[2]=g0.z; gj[3]=g0.w;
        gj[4]=g1.x; gj[5]=g1.y; gj[6]=g1.z; gj[7]=g1.w;
    }

    #pragma unroll 2
    for (int ii = 0; ii < 16; ++ii) {
        const int i = i0 + ii;
        const float ti  = etime[rowb + i];
        const float pbi = pbE[rowb + i];
        const float gbi = gbE[rowb + i];
        const size_t base = ((size_t)(rowb + i) << 11) + j0;

        float d[8];
        #pragma unroll
        for (int e = 0; e < 8; ++e) d[e] = fabsf(tj[e] - ti);

        v4 t0 = { d[0], d[1], d[2], d[3] };
        v4 t1 = { d[4], d[5], d[6], d[7] };
        __builtin_nontemporal_store(t0, (v4*)(tdiff + base));
        __builtin_nontemporal_store(t1, (v4*)(tdiff + base + 4));

        v4 s0, s1;
        if (j0 < i) {
            float s[8];
            #pragma unroll
            for (int e = 0; e < 8; ++e) {
                float l  = __logf(fmaf(pj[e], pbi, 1.0f)) + EPSV;  // softplus
                float rl = __builtin_amdgcn_rcpf(l);
                float u  = d[e] * rl;
                float kse = __expf(-0.5f * u * u);
                float kex = __expf(-u);
                float g   = __builtin_amdgcn_rcpf(fmaf(gj[e], gbi, 1.0f));
                float v   = g * fmaf(BETA0, kse, BETA1 * kex);
                s[e] = ((j0 + e) < i) ? v : 0.0f;
            }
            s0.x=s[0]; s0.y=s[1]; s0.z=s[2]; s0.w=s[3];
            s1.x=s[4]; s1.y=s[5]; s1.z=s[6]; s1.w=s[7];
        } else {
            s0 = (v4)(0.0f);
            s1 = (v4)(0.0f);
        }
        __builtin_nontemporal_store(s0, (v4*)(scores + base));
        __builtin_nontemporal_store(s1, (v4*)(scores + base + 4));
    }
}

extern "C" void kernel_launch(void* const* d_in, const int* in_sizes, int n_in,
                              void* d_out, int out_size, void* d_ws, size_t ws_size,
                              hipStream_t stream) {
    const int*   etype = (const int*)d_in[0];
    const float* etime = (const float*)d_in[1];
    // d_in[2] arrival_times: unused by the reference
    const float* wtpos = (const float*)d_in[3];
    const float* temb  = (const float*)d_in[4];
    const float* wl    = (const float*)d_in[5];
    const float* blp   = (const float*)d_in[6];
    const float* wg    = (const float*)d_in[7];
    const float* bgp   = (const float*)d_in[8];

    float* out    = (float*)d_out;
    float* scores = out;                                  // [8,2048,2048]
    float* hidden = out + (size_t)BB * LL * LL;           // [8,2048,544]
    float* tdiff  = hidden + (size_t)BB * LL * HID;       // [8,2048,2048]

    float* paE = (float*)d_ws;
    float* pbE = paE + BB * LL;
    float* gaE = pbE + BB * LL;
    float* gbE = gaE + BB * LL;

    prep_k<<<BB * LL / 8, 256, 0, stream>>>(etype, etime, wtpos, temb, wl, wg,
                                            blp, bgp, hidden, paE, pbE, gaE, gbE);
    pair_k<<<dim3(LL / 16, BB), 256, 0, stream>>>(etime, paE, pbE, gaE, gbE,
                                                  scores, tdiff);
}